// Round 17
// baseline (73.534 us; speedup 1.0000x reference)
//
#include <hip/hip_runtime.h>
#include <hip/hip_bf16.h>

typedef __attribute__((ext_vector_type(4)))  float f32x4;
typedef __attribute__((ext_vector_type(16))) float f32x16;
typedef __attribute__((ext_vector_type(8)))  short s16x8;
typedef __attribute__((ext_vector_type(4)))  short s16x4;
typedef __attribute__((ext_vector_type(4)))  int   i32x4;

#define BB 2
#define HH 8
#define SS 2048
#define DD 64
#define QBLK 128
#define NT   32               // 64-key prep images per bh
#define NT2  16               // 128-key tiles in main loop
#define NBH  (BB * HH)        // 16

// ws layout: per-(bh,64-key-tile) 8KB pre-swizzled bf16 LDS images
// (K row-major, V transposed) — R2/R7-verified format, unchanged.
#define WS_KX 0
#define WS_KY ((size_t)NBH * NT * 8192)          // 4 MiB each
#define WS_VX ((size_t)2 * NBH * NT * 8192)
#define WS_VY ((size_t)3 * NBH * NT * 8192)
#define WS_NEED ((size_t)4 * NBH * NT * 8192)    // 16 MiB

// fp32 -> bf16 round-to-nearest-even
__device__ __forceinline__ short f2bf(float x) {
    unsigned u = __builtin_bit_cast(unsigned, x);
    u = (u + 0x7FFFu + ((u >> 16) & 1u)) >> 16;
    return (short)u;
}

// pack two f32 -> one dword of 2 bf16 (RNE)
__device__ __forceinline__ unsigned cvtpk(float lo, float hi) {
    unsigned d;
    asm("v_cvt_pk_bf16_f32 %0, %1, %2" : "=v"(d) : "v"(lo), "v"(hi));
    return d;
}

// XOR swizzle within a 128-byte row (guide G4)
__device__ __forceinline__ int swz(int row, int byteInRow) {
    return row * 128 + (byteInRow ^ ((row & 7) << 4));
}

// 16-byte async global->LDS copy
__device__ __forceinline__ void glds16(const void* g, void* l) {
    __builtin_amdgcn_global_load_lds(
        (const __attribute__((address_space(1))) unsigned*)g,
        (__attribute__((address_space(3))) unsigned*)l, 16, 0, 0);
}

// ------------- fused prepass (R7-verified): K row-major / V transposed -------
__global__ __launch_bounds__(256)
void prep_kv(const float* __restrict__ Kx, const float* __restrict__ Ky,
             const float* __restrict__ Vx, const float* __restrict__ Vy,
             char* __restrict__ ws)
{
    const int b = blockIdx.x;
    if (b < 1024) {
        const int tid  = b * 256 + threadIdx.x;
        const int dblk = tid & 7;
        const int s    = (tid >> 3) & 2047;
        const int bh   = tid >> 14;
        const size_t gi = ((size_t)bh * SS + s) * DD + dblk * 8;
        const int kt = s >> 6, row = s & 63;
        const size_t dst = (size_t)(bh * NT + kt) * 8192 + swz(row, dblk * 16);
        const float* px = Kx + gi;
        const float* py = Ky + gi;
        s16x8 a, bb;
#pragma unroll
        for (int i = 0; i < 8; ++i) { a[i] = f2bf(px[i]); bb[i] = f2bf(py[i]); }
        *(s16x8*)(ws + WS_KX + dst) = a;
        *(s16x8*)(ws + WS_KY + dst) = bb;
    } else {
        const int tid  = (b - 1024) * 256 + threadIdx.x;
        const int d    = tid & 63;
        const int sblk = (tid >> 6) & 7;
        const int kt   = (tid >> 9) & 31;
        const int bh   = tid >> 14;
        const size_t gbase = ((size_t)bh * SS + kt * 64 + sblk * 8) * DD + d;
        s16x8 a, bb;
#pragma unroll
        for (int i = 0; i < 8; ++i) {
            a[i]  = f2bf(Vx[gbase + (size_t)i * DD]);
            bb[i] = f2bf(Vy[gbase + (size_t)i * DD]);
        }
        const size_t dst = (size_t)(bh * NT + kt) * 8192 + swz(d, sblk * 16);
        *(s16x8*)(ws + WS_VX + dst) = a;
        *(s16x8*)(ws + WS_VY + dst) = bb;
    }
}

// ------------------------------- main kernel ---------------------------------
// 1024-thread blocks: 16 waves = qsub(4: 32 q-rows) x ks(4: 32-key quarter).
// QBLK=128, KBLK=128, grid 256 = 1 block/CU, LDS 128KB dbuf -> 16 waves/CU =
// 4 waves/SIMD (2x R16's TLP) with V-in-LDS and ZERO work duplication — the
// geometry R7-R9 missed (they paid with duplication or V-direct latency).
// Loop body: QK -> V_READS -> softmax/permlane -> PV; all ds_reads consumed
// before the barrier (R12 race lesson). Epilogue: R9-verified 4-partial
// combine + R16 inverse-broadcast.
__global__ __launch_bounds__(1024, 4)
void attn_main(const float* __restrict__ Qx, const float* __restrict__ Qy,
               const char* __restrict__ ws, float* __restrict__ Out)
{
    extern __shared__ char lds[];

    const int t    = threadIdx.x;
    const int lane = t & 63;
    const int w    = t >> 6;      // 0..15
    const int qsub = w & 3;       // 32 q-rows each
    const int ks   = w >> 2;      // 0..3: 32-key quarter of the 128-key tile
    const int l31  = lane & 31;
    const int hi   = lane >> 5;   // 0/1

    // XCD-chunked swizzle (256 % 8 == 0, bijective): 32 consecutive per XCD
    int bid = blockIdx.x;
    bid = (bid & 7) * 32 + (bid >> 3);
    const int bh = bid >> 4;
    const int q0 = (bid & 15) * QBLK;
    const size_t base = (size_t)bh * SS * DD;

    // ---- Q B-frags: col q = lane&31, k = d = dc*16 + hi*8 + i
    const int qrow = q0 + qsub * 32 + l31;
    s16x8 qbx[4], qby[4];
#pragma unroll
    for (int dc = 0; dc < 4; ++dc) {
        const int d0 = dc * 16 + hi * 8;
        const float* qp = Qx + base + (size_t)qrow * DD + d0;
        const float* qq = Qy + base + (size_t)qrow * DD + d0;
        const float4 f0 = *(const float4*)qp;
        const float4 f1 = *(const float4*)(qp + 4);
        const float4 h0 = *(const float4*)qq;
        const float4 h1 = *(const float4*)(qq + 4);
        qbx[dc][0]=f2bf(f0.x); qbx[dc][1]=f2bf(f0.y); qbx[dc][2]=f2bf(f0.z); qbx[dc][3]=f2bf(f0.w);
        qbx[dc][4]=f2bf(f1.x); qbx[dc][5]=f2bf(f1.y); qbx[dc][6]=f2bf(f1.z); qbx[dc][7]=f2bf(f1.w);
        qby[dc][0]=f2bf(h0.x); qby[dc][1]=f2bf(h0.y); qby[dc][2]=f2bf(h0.z); qby[dc][3]=f2bf(h0.w);
        qby[dc][4]=f2bf(h1.x); qby[dc][5]=f2bf(h1.y); qby[dc][6]=f2bf(h1.z); qby[dc][7]=f2bf(h1.w);
    }

    f32x16 o1_0, o1_1, o2_0, o2_1;
#pragma unroll
    for (int j = 0; j < 16; ++j) { o1_0[j] = 0.f; o1_1[j] = 0.f; o2_0[j] = 0.f; o2_1[j] = 0.f; }
    float lsum = 0.f;

    const float SCL = 0.09016844005556021f;   // log2(e) / (2*sqrt(64))

    // wave's K/V image within the 128-key tile: image (ks>>1), keys (ks&1)*32..
    const int kimg = (ks >> 1) * 8192;
    const int krow = (ks & 1) * 32 + l31;
    const int kbyt = (ks & 1) * 64;          // V byteInRow base for this quarter

    // stage 128-key tile kt_ (2 prep images per tensor) into buffer b_ (64KB).
    // buffer layout: Kx[imgA,imgB] | Ky | Vtx | Vty (16KB regions).
    // 1024 threads x 16B spans one 16KB region per glds16.
#define STAGE(kt_, b_)                                                             \
    do {                                                                           \
        const size_t img_ = (size_t)(bh * NT + (kt_) * 2) * 8192 + (size_t)t * 16; \
        char* dst_ = lds + (b_) * 65536 + t * 16;                                  \
        glds16(ws + WS_KX + img_, dst_);                                           \
        glds16(ws + WS_KY + img_, dst_ + 16384);                                   \
        glds16(ws + WS_VX + img_, dst_ + 32768);                                   \
        glds16(ws + WS_VY + img_, dst_ + 49152);                                   \
    } while (0)

    // QK for this wave's 32-key quarter: sc accumulate
#define QK_BLOCK(buf_, sc_)                                                        \
    do {                                                                           \
        const char* KxI_ = (buf_) + kimg;                                          \
        const char* KyI_ = (buf_) + 16384 + kimg;                                  \
        _Pragma("unroll")                                                          \
        for (int dc = 0; dc < 4; ++dc) {                                           \
            const int off = swz(krow, dc * 32 + hi * 16);                          \
            const s16x8 ka = *(const s16x8*)(KxI_ + off);                          \
            const s16x8 kb = *(const s16x8*)(KyI_ + off);                          \
            sc_ = __builtin_amdgcn_mfma_f32_32x32x16_bf16(ka, qbx[dc], sc_, 0, 0, 0); \
            sc_ = __builtin_amdgcn_mfma_f32_32x32x16_bf16(kb, qby[dc], sc_, 0, 0, 0); \
        }                                                                          \
    } while (0)

    // V frag reads for this quarter (8 x ds_read_b128) into vr_[0..7]
#define V_READS(buf_, vr_)                                                         \
    do {                                                                           \
        const char* VxI_ = (buf_) + 32768 + kimg;                                  \
        const char* VyI_ = (buf_) + 49152 + kimg;                                  \
        _Pragma("unroll")                                                          \
        for (int ch = 0; ch < 2; ++ch) {                                           \
            const int off0 = swz(l31,      kbyt + ch * 32 + hi * 16);              \
            const int off1 = swz(32 + l31, kbyt + ch * 32 + hi * 16);              \
            vr_[ch * 4 + 0] = *(const s16x8*)(VxI_ + off0);                        \
            vr_[ch * 4 + 1] = *(const s16x8*)(VxI_ + off1);                        \
            vr_[ch * 4 + 2] = *(const s16x8*)(VyI_ + off0);                        \
            vr_[ch * 4 + 3] = *(const s16x8*)(VyI_ + off1);                        \
        }                                                                          \
    } while (0)

    // softmax in place + pa redistribution via permlane32_swap (R14-verified)
#define SOFTMAX_PA(sc_, pa_)                                                       \
    do {                                                                           \
        float s_ = 0.f;                                                            \
        _Pragma("unroll")                                                          \
        for (int j = 0; j < 16; ++j) { sc_[j] = exp2f(sc_[j] * SCL); s_ += sc_[j]; } \
        lsum += s_;                                                                \
        _Pragma("unroll")                                                          \
        for (int ch = 0; ch < 2; ++ch) {                                           \
            const int b8 = ch * 8;                                                 \
            unsigned x0 = cvtpk(sc_[b8 + 0], sc_[b8 + 1]);                         \
            unsigned x1 = cvtpk(sc_[b8 + 2], sc_[b8 + 3]);                         \
            unsigned y0 = cvtpk(sc_[b8 + 4], sc_[b8 + 5]);                         \
            unsigned y1 = cvtpk(sc_[b8 + 6], sc_[b8 + 7]);                         \
            asm("v_permlane32_swap_b32 %0, %1" : "+v"(x0), "+v"(y0));              \
            asm("v_permlane32_swap_b32 %0, %1" : "+v"(x1), "+v"(y1));              \
            i32x4 pw;                                                              \
            pw[0] = (int)x0; pw[1] = (int)x1; pw[2] = (int)y0; pw[3] = (int)y1;    \
            pa_[ch] = __builtin_bit_cast(s16x8, pw);                               \
        }                                                                          \
    } while (0)

    // PV accumulate: o += pa_ x vr_  (register-only, 8 MFMA)
#define PV_BLOCK(pa_, vr_)                                                         \
    do {                                                                           \
        _Pragma("unroll")                                                          \
        for (int ch = 0; ch < 2; ++ch) {                                           \
            o1_0 = __builtin_amdgcn_mfma_f32_32x32x16_bf16(pa_[ch], vr_[ch*4+0], o1_0, 0, 0, 0); \
            o1_1 = __builtin_amdgcn_mfma_f32_32x32x16_bf16(pa_[ch], vr_[ch*4+1], o1_1, 0, 0, 0); \
            o2_0 = __builtin_amdgcn_mfma_f32_32x32x16_bf16(pa_[ch], vr_[ch*4+2], o2_0, 0, 0, 0); \
            o2_1 = __builtin_amdgcn_mfma_f32_32x32x16_bf16(pa_[ch], vr_[ch*4+3], o2_1, 0, 0, 0); \
        }                                                                          \
    } while (0)

#define ZERO16(v_) { _Pragma("unroll") for (int j = 0; j < 16; ++j) (v_)[j] = 0.f; }

    STAGE(0, 0);
    __syncthreads();
    int cur = 0;

    for (int kt = 0; kt < NT2; ++kt) {
        if (kt + 1 < NT2) STAGE(kt + 1, cur ^ 1);

        const char* buf = lds + cur * 65536;
        f32x16 sc;
        ZERO16(sc);
        s16x8 pa[2], vr[8];

        __builtin_amdgcn_s_setprio(1);
        QK_BLOCK(buf, sc);
        V_READS(buf, vr);                // latency hides under softmax below
        SOFTMAX_PA(sc, pa);
        PV_BLOCK(pa, vr);                // consumes all ds_reads before barrier
        __builtin_amdgcn_s_setprio(0);

        __syncthreads();    // next buffer staged (vmcnt drained); cur reads done
        cur ^= 1;
    }

#undef STAGE
#undef QK_BLOCK
#undef V_READS
#undef SOFTMAX_PA
#undef PV_BLOCK
#undef ZERO16

    // ---- epilogue: combine 4 ks partials (R9-verified scheme), per-q-row inv
    const float lh = lsum + __shfl_xor(lsum, 32);   // quarter sum for q=l31

    __syncthreads();                                 // loop LDS now dead
    float* ex   = (float*)lds;                       // 12*64*33*4 = 101376 B
    float* linv = (float*)(lds + 110592);            // 128 per-q-row inverses
    const int exo = (((ks - 1) * 4 + qsub) * 64 + lane) * 33;  // valid for ks>=1
    float* O1 = Out;
    float* O2 = Out + (size_t)BB * HH * SS * DD;

    // phase 1: tensor X (+ lh)
    if (ks != 0) {
#pragma unroll
        for (int j = 0; j < 16; ++j) { ex[exo + j] = o1_0[j]; ex[exo + 16 + j] = o1_1[j]; }
        ex[exo + 32] = lh;
    }
    __syncthreads();
    if (ks == 0 && hi == 0) {
        float ltot = lh;
#pragma unroll
        for (int kk = 1; kk < 4; ++kk)
            ltot += ex[(((kk - 1) * 4 + qsub) * 64 + lane) * 33 + 32];
        linv[qsub * 32 + l31] = 1.0f / ltot;
    }
    __syncthreads();
    if (ks == 0) {
#pragma unroll
        for (int j = 0; j < 16; ++j) {
            const int qr = (j & 3) + 8 * (j >> 2) + 4 * hi;   // output q-row of reg j
            const float invj = linv[qsub * 32 + qr];
            float a0 = o1_0[j], a1 = o1_1[j];
#pragma unroll
            for (int kk = 1; kk < 4; ++kk) {
                const int eo = (((kk - 1) * 4 + qsub) * 64 + lane) * 33;
                a0 += ex[eo + j];
                a1 += ex[eo + 16 + j];
            }
            const size_t ob = base + (size_t)(q0 + qsub * 32 + qr) * DD + l31;
            O1[ob]      = a0 * invj;
            O1[ob + 32] = a1 * invj;
        }
    }
    __syncthreads();
    // phase 2: tensor Y
    if (ks != 0) {
#pragma unroll
        for (int j = 0; j < 16; ++j) { ex[exo + j] = o2_0[j]; ex[exo + 16 + j] = o2_1[j]; }
    }
    __syncthreads();
    if (ks == 0) {
#pragma unroll
        for (int j = 0; j < 16; ++j) {
            const int qr = (j & 3) + 8 * (j >> 2) + 4 * hi;
            const float invj = linv[qsub * 32 + qr];
            float a0 = o2_0[j], a1 = o2_1[j];
#pragma unroll
            for (int kk = 1; kk < 4; ++kk) {
                const int eo = (((kk - 1) * 4 + qsub) * 64 + lane) * 33;
                a0 += ex[eo + j];
                a1 += ex[eo + 16 + j];
            }
            const size_t ob = base + (size_t)(q0 + qsub * 32 + qr) * DD + l31;
            O2[ob]      = a0 * invj;
            O2[ob + 32] = a1 * invj;
        }
    }
}

// ===================== fallback (ws too small; validated R1 path) ============
__global__ __launch_bounds__(256, 2)
void attn_dual_fallback(const float* __restrict__ Qx, const float* __restrict__ Kx,
                        const float* __restrict__ Vx, const float* __restrict__ Qy,
                        const float* __restrict__ Ky, const float* __restrict__ Vy,
                        float* __restrict__ Out)
{
    __shared__ __attribute__((aligned(16))) char lds[40960];
    char* KxL  = lds;
    char* KyL  = lds + 8192;
    char* VtxL = lds + 16384;
    char* VtyL = lds + 24576;

    const int t    = threadIdx.x;
    const int lane = t & 63;
    const int w    = t >> 6;
    const int g    = lane >> 4;
    const int c    = lane & 15;
    char* PL = lds + 32768 + w * 2048;

    const int bid = blockIdx.x;
    const int bh  = bid >> 5;
    const int q0  = (bid & 31) * 64;
    const size_t base = (size_t)bh * SS * DD;

    const int qrowA = q0 + w * 16 + c;
    s16x8 qxf[2], qyf[2];
#pragma unroll
    for (int kk = 0; kk < 2; ++kk) {
        const int d0 = kk * 32 + g * 8;
        const float* qp = Qx + base + (size_t)qrowA * DD + d0;
        const float* qq = Qy + base + (size_t)qrowA * DD + d0;
#pragma unroll
        for (int i = 0; i < 8; ++i) { qxf[kk][i] = f2bf(qp[i]); qyf[kk][i] = f2bf(qq[i]); }
    }

    f32x4 o1[4], o2[4];
#pragma unroll
    for (int n = 0; n < 4; ++n) {
        o1[n] = (f32x4){0.f, 0.f, 0.f, 0.f};
        o2[n] = (f32x4){0.f, 0.f, 0.f, 0.f};
    }
    float m[4]    = {-1e30f, -1e30f, -1e30f, -1e30f};
    float lsum[4] = {0.f, 0.f, 0.f, 0.f};
    const float SCL = 0.09016844005556021f;

    for (int kt = 0; kt < SS / 64; ++kt) {
        __syncthreads();
#pragma unroll
        for (int j = 0; j < 4; ++j) {
            const int f   = t + 256 * j;
            const int row = f >> 4;
            const int c4  = f & 15;
            const size_t gi = base + (size_t)(kt * 64 + row) * DD + c4 * 4;
            const float4 kx = *(const float4*)(Kx + gi);
            const float4 ky = *(const float4*)(Ky + gi);
            const float4 vx = *(const float4*)(Vx + gi);
            const float4 vy = *(const float4*)(Vy + gi);
            s16x4 a; a[0]=f2bf(kx.x); a[1]=f2bf(kx.y); a[2]=f2bf(kx.z); a[3]=f2bf(kx.w);
            *(s16x4*)(KxL + swz(row, c4 * 8)) = a;
            s16x4 b; b[0]=f2bf(ky.x); b[1]=f2bf(ky.y); b[2]=f2bf(ky.z); b[3]=f2bf(ky.w);
            *(s16x4*)(KyL + swz(row, c4 * 8)) = b;
            const int d0 = c4 * 4;
            *(short*)(VtxL + swz(d0 + 0, row * 2)) = f2bf(vx.x);
            *(short*)(VtxL + swz(d0 + 1, row * 2)) = f2bf(vx.y);
            *(short*)(VtxL + swz(d0 + 2, row * 2)) = f2bf(vx.z);
            *(short*)(VtxL + swz(d0 + 3, row * 2)) = f2bf(vx.w);
            *(short*)(VtyL + swz(d0 + 0, row * 2)) = f2bf(vy.x);
            *(short*)(VtyL + swz(d0 + 1, row * 2)) = f2bf(vy.y);
            *(short*)(VtyL + swz(d0 + 2, row * 2)) = f2bf(vy.z);
            *(short*)(VtyL + swz(d0 + 3, row * 2)) = f2bf(vy.w);
        }
        __syncthreads();

        f32x4 sc[4];
#pragma unroll
        for (int n = 0; n < 4; ++n) {
            f32x4 acc = (f32x4){0.f, 0.f, 0.f, 0.f};
            const int keyrow = n * 16 + c;
#pragma unroll
            for (int kk = 0; kk < 2; ++kk) {
                const int off = swz(keyrow, (kk * 32 + g * 8) * 2);
                const s16x8 kxf = *(const s16x8*)(KxL + off);
                const s16x8 kyf = *(const s16x8*)(KyL + off);
                acc = __builtin_amdgcn_mfma_f32_16x16x32_bf16(qxf[kk], kxf, acc, 0, 0, 0);
                acc = __builtin_amdgcn_mfma_f32_16x16x32_bf16(qyf[kk], kyf, acc, 0, 0, 0);
            }
            sc[n] = acc;
        }

#pragma unroll
        for (int r = 0; r < 4; ++r) {
            float v0 = fmaxf(fmaxf(sc[0][r], sc[1][r]), fmaxf(sc[2][r], sc[3][r])) * SCL;
#pragma unroll
            for (int off = 1; off < 16; off <<= 1) v0 = fmaxf(v0, __shfl_xor(v0, off));
            const float mnew = fmaxf(m[r], v0);
            const float cr = exp2f(m[r] - mnew);
            m[r] = mnew;
            float srow = 0.f;
#pragma unroll
            for (int n = 0; n < 4; ++n) {
                const float pp = exp2f(sc[n][r] * SCL - mnew);
                srow += pp;
                *(short*)(PL + swz(g * 4 + r, (n * 16 + c) * 2)) = f2bf(pp);
            }
#pragma unroll
            for (int off = 1; off < 16; off <<= 1) srow += __shfl_xor(srow, off);
            lsum[r] = lsum[r] * cr + srow;
#pragma unroll
            for (int n = 0; n < 4; ++n) { o1[n][r] *= cr; o2[n][r] *= cr; }
        }

        s16x8 pf[2];
#pragma unroll
        for (int kk = 0; kk < 2; ++kk)
            pf[kk] = *(const s16x8*)(PL + swz(c, (kk * 32 + g * 8) * 2));
#pragma unroll
        for (int nd = 0; nd < 4; ++nd) {
            const int drow = nd * 16 + c;
#pragma unroll
            for (int kk = 0; kk < 2; ++kk) {
                const int off = swz(drow, (kk * 32 + g * 8) * 2);
                const s16x8 vxf = *(const s16x8*)(VtxL + off);
                const s16x8 vyf = *(const s16x8*)(VtyL + off);
                o1[nd] = __builtin_amdgcn_mfma_f32_16x16x32_bf16(pf[kk], vxf, o1[nd], 0, 0, 0);
                o2[nd] = __builtin_amdgcn_mfma_f32_16x16x32_bf16(pf[kk], vyf, o2[nd], 0, 0, 0);
            }
        }
    }

    float* O1 = Out;
    float* O2 = Out + (size_t)BB * HH * SS * DD;
#pragma unroll
    for (int r = 0; r < 4; ++r) {
        const float inv = 1.0f / lsum[r];
        const int qrow = q0 + w * 16 + g * 4 + r;
        const size_t ob = base + (size_t)qrow * DD + c;
#pragma unroll
        for (int nd = 0; nd < 4; ++nd) {
            O1[ob + nd * 16] = o1[nd][r] * inv;
            O2[ob + nd * 16] = o2[nd][r] * inv;
        }
    }
}

extern "C" void kernel_launch(void* const* d_in, const int* in_sizes, int n_in,
                              void* d_out, int out_size, void* d_ws, size_t ws_size,
                              hipStream_t stream) {
    const float* Qx = (const float*)d_in[0];
    const float* Kx = (const float*)d_in[1];
    const float* Vx = (const float*)d_in[2];
    const float* Qy = (const float*)d_in[3];
    const float* Ky = (const float*)d_in[4];
    const float* Vy = (const float*)d_in[5];
    float* Out = (float*)d_out;

    if (ws_size >= WS_NEED) {
        char* ws = (char*)d_ws;
        hipLaunchKernelGGL(prep_kv, dim3(2048), dim3(256), 0, stream,
                           Kx, Ky, Vx, Vy, ws);
        hipFuncSetAttribute((const void*)attn_main,
                            hipFuncAttributeMaxDynamicSharedMemorySize, 131072);
        hipLaunchKernelGGL(attn_main, dim3(NBH * (SS / QBLK)), dim3(1024), 131072,
                           stream, Qx, Qy, (const char*)ws, Out);
    } else {
        hipLaunchKernelGGL(attn_dual_fallback, dim3(NBH * 32), dim3(256),
                           0, stream, Qx, Kx, Vx, Qy, Ky, Vy, Out);
    }
}

// Round 18
// 59.345 us; speedup vs baseline: 1.2391x; 1.2391x over previous
//
#include <hip/hip_runtime.h>
#include <hip/hip_bf16.h>

typedef __attribute__((ext_vector_type(4)))  float f32x4;
typedef __attribute__((ext_vector_type(16))) float f32x16;
typedef __attribute__((ext_vector_type(8)))  short s16x8;
typedef __attribute__((ext_vector_type(4)))  short s16x4;
typedef __attribute__((ext_vector_type(4)))  int   i32x4;

#define BB 2
#define HH 8
#define SS 2048
#define DD 64
#define QBLK 128
#define NT   32               // 64-key prep images per bh
#define NT2  16               // 128-key tiles in main loop
#define NBH  (BB * HH)        // 16

// ws layout: per-(bh,64-key-tile) 8KB pre-swizzled bf16 LDS images
// (K row-major, V transposed) — R2/R7-verified format, unchanged.
#define WS_KX 0
#define WS_KY ((size_t)NBH * NT * 8192)          // 4 MiB each
#define WS_VX ((size_t)2 * NBH * NT * 8192)
#define WS_VY ((size_t)3 * NBH * NT * 8192)
#define WS_NEED ((size_t)4 * NBH * NT * 8192)    // 16 MiB

// fp32 -> bf16 round-to-nearest-even
__device__ __forceinline__ short f2bf(float x) {
    unsigned u = __builtin_bit_cast(unsigned, x);
    u = (u + 0x7FFFu + ((u >> 16) & 1u)) >> 16;
    return (short)u;
}

// pack two f32 -> one dword of 2 bf16 (RNE)
__device__ __forceinline__ unsigned cvtpk(float lo, float hi) {
    unsigned d;
    asm("v_cvt_pk_bf16_f32 %0, %1, %2" : "=v"(d) : "v"(lo), "v"(hi));
    return d;
}

// XOR swizzle within a 128-byte row (guide G4)
__device__ __forceinline__ int swz(int row, int byteInRow) {
    return row * 128 + (byteInRow ^ ((row & 7) << 4));
}

// 16-byte async global->LDS copy
__device__ __forceinline__ void glds16(const void* g, void* l) {
    __builtin_amdgcn_global_load_lds(
        (const __attribute__((address_space(1))) unsigned*)g,
        (__attribute__((address_space(3))) unsigned*)l, 16, 0, 0);
}

// ------------- fused prepass (R7-verified): K row-major / V transposed -------
__global__ __launch_bounds__(256)
void prep_kv(const float* __restrict__ Kx, const float* __restrict__ Ky,
             const float* __restrict__ Vx, const float* __restrict__ Vy,
             char* __restrict__ ws)
{
    const int b = blockIdx.x;
    if (b < 1024) {
        const int tid  = b * 256 + threadIdx.x;
        const int dblk = tid & 7;
        const int s    = (tid >> 3) & 2047;
        const int bh   = tid >> 14;
        const size_t gi = ((size_t)bh * SS + s) * DD + dblk * 8;
        const int kt = s >> 6, row = s & 63;
        const size_t dst = (size_t)(bh * NT + kt) * 8192 + swz(row, dblk * 16);
        const float* px = Kx + gi;
        const float* py = Ky + gi;
        s16x8 a, bb;
#pragma unroll
        for (int i = 0; i < 8; ++i) { a[i] = f2bf(px[i]); bb[i] = f2bf(py[i]); }
        *(s16x8*)(ws + WS_KX + dst) = a;
        *(s16x8*)(ws + WS_KY + dst) = bb;
    } else {
        const int tid  = (b - 1024) * 256 + threadIdx.x;
        const int d    = tid & 63;
        const int sblk = (tid >> 6) & 7;
        const int kt   = (tid >> 9) & 31;
        const int bh   = tid >> 14;
        const size_t gbase = ((size_t)bh * SS + kt * 64 + sblk * 8) * DD + d;
        s16x8 a, bb;
#pragma unroll
        for (int i = 0; i < 8; ++i) {
            a[i]  = f2bf(Vx[gbase + (size_t)i * DD]);
            bb[i] = f2bf(Vy[gbase + (size_t)i * DD]);
        }
        const size_t dst = (size_t)(bh * NT + kt) * 8192 + swz(d, sblk * 16);
        *(s16x8*)(ws + WS_VX + dst) = a;
        *(s16x8*)(ws + WS_VY + dst) = bb;
    }
}

// ------------------------------- main kernel ---------------------------------
// R16 (verified best): KBLK=128, 8 waves = qsub(4: 32 q-rows) x ks(2: 64-key
// half). Grid 256, LDS 128KB dbuf -> 1 block/CU, 8 waves/CU, 16 barriers.
// Each tile's two 32-key halves pipelined intra-tile (QK(h0),QK(h1) ||
// softmax(h0),PV(h0) || softmax(h1),PV(h1)); all ds_reads consumed before the
// barrier (R12 race lesson). Permlane P-redistribution (R14-verified).
// R17 lesson: raising waves/SIMD behind ONE barrier phase-aligns the waves
// and REGRESSES — this 8-wave shape is the measured optimum of the family.
__global__ __launch_bounds__(512, 2)
void attn_main(const float* __restrict__ Qx, const float* __restrict__ Qy,
               const char* __restrict__ ws, float* __restrict__ Out)
{
    extern __shared__ char lds[];

    const int t    = threadIdx.x;
    const int lane = t & 63;
    const int w    = t >> 6;      // 0..7
    const int qsub = w & 3;       // 32 q-rows each
    const int ks   = w >> 2;      // 64-key half of the 128-key tile
    const int l31  = lane & 31;
    const int hi   = lane >> 5;   // 0/1

    // XCD-chunked swizzle (256 % 8 == 0, bijective): 32 consecutive per XCD
    int bid = blockIdx.x;
    bid = (bid & 7) * 32 + (bid >> 3);
    const int bh = bid >> 4;
    const int q0 = (bid & 15) * QBLK;
    const size_t base = (size_t)bh * SS * DD;

    // ---- Q B-frags: col q = lane&31, k = d = dc*16 + hi*8 + i
    const int qrow = q0 + qsub * 32 + l31;
    s16x8 qbx[4], qby[4];
#pragma unroll
    for (int dc = 0; dc < 4; ++dc) {
        const int d0 = dc * 16 + hi * 8;
        const float* qp = Qx + base + (size_t)qrow * DD + d0;
        const float* qq = Qy + base + (size_t)qrow * DD + d0;
        const float4 f0 = *(const float4*)qp;
        const float4 f1 = *(const float4*)(qp + 4);
        const float4 h0 = *(const float4*)qq;
        const float4 h1 = *(const float4*)(qq + 4);
        qbx[dc][0]=f2bf(f0.x); qbx[dc][1]=f2bf(f0.y); qbx[dc][2]=f2bf(f0.z); qbx[dc][3]=f2bf(f0.w);
        qbx[dc][4]=f2bf(f1.x); qbx[dc][5]=f2bf(f1.y); qbx[dc][6]=f2bf(f1.z); qbx[dc][7]=f2bf(f1.w);
        qby[dc][0]=f2bf(h0.x); qby[dc][1]=f2bf(h0.y); qby[dc][2]=f2bf(h0.z); qby[dc][3]=f2bf(h0.w);
        qby[dc][4]=f2bf(h1.x); qby[dc][5]=f2bf(h1.y); qby[dc][6]=f2bf(h1.z); qby[dc][7]=f2bf(h1.w);
    }

    f32x16 o1_0, o1_1, o2_0, o2_1;
#pragma unroll
    for (int j = 0; j < 16; ++j) { o1_0[j] = 0.f; o1_1[j] = 0.f; o2_0[j] = 0.f; o2_1[j] = 0.f; }
    float lsum = 0.f;

    const float SCL = 0.09016844005556021f;   // log2(e) / (2*sqrt(64))

    // stage 128-key tile kt_ (2 prep images per tensor) into buffer b_ (64KB)
    // buffer layout: Kx[img0,img1] | Ky[...] | Vtx[...] | Vty[...] (8KB each)
#define STAGE(kt_, b_)                                                             \
    do {                                                                           \
        const size_t img_ = (size_t)(bh * NT + (kt_) * 2) * 8192 + (size_t)t * 16; \
        char* dst_ = lds + (b_) * 65536 + t * 16;                                  \
        glds16(ws + WS_KX + img_,        dst_);                                    \
        glds16(ws + WS_KX + img_ + 8192, dst_ + 8192);                             \
        glds16(ws + WS_KY + img_,        dst_ + 16384);                            \
        glds16(ws + WS_KY + img_ + 8192, dst_ + 24576);                            \
        glds16(ws + WS_VX + img_,        dst_ + 32768);                            \
        glds16(ws + WS_VX + img_ + 8192, dst_ + 40960);                            \
        glds16(ws + WS_VY + img_,        dst_ + 49152);                            \
        glds16(ws + WS_VY + img_ + 8192, dst_ + 57344);                            \
    } while (0)

    // QK for 32-key half h_ of this wave's image (image ks): sc accumulate
#define QK_BLOCK(buf_, h_, sc_)                                                    \
    do {                                                                           \
        const char* KxI_ = (buf_) + ks * 8192;                                     \
        const char* KyI_ = (buf_) + 16384 + ks * 8192;                             \
        _Pragma("unroll")                                                          \
        for (int dc = 0; dc < 4; ++dc) {                                           \
            const int off = swz((h_) * 32 + l31, dc * 32 + hi * 16);               \
            const s16x8 ka = *(const s16x8*)(KxI_ + off);                          \
            const s16x8 kb = *(const s16x8*)(KyI_ + off);                          \
            sc_ = __builtin_amdgcn_mfma_f32_32x32x16_bf16(ka, qbx[dc], sc_, 0, 0, 0); \
            sc_ = __builtin_amdgcn_mfma_f32_32x32x16_bf16(kb, qby[dc], sc_, 0, 0, 0); \
        }                                                                          \
    } while (0)

    // V frag reads for half h_ (8 x ds_read_b128) into vr_[0..7]
#define V_READS(buf_, h_, vr_)                                                     \
    do {                                                                           \
        const char* VxI_ = (buf_) + 32768 + ks * 8192;                             \
        const char* VyI_ = (buf_) + 49152 + ks * 8192;                             \
        _Pragma("unroll")                                                          \
        for (int ch = 0; ch < 2; ++ch) {                                           \
            const int off0 = swz(l31,      (h_) * 64 + ch * 32 + hi * 16);         \
            const int off1 = swz(32 + l31, (h_) * 64 + ch * 32 + hi * 16);         \
            vr_[ch * 4 + 0] = *(const s16x8*)(VxI_ + off0);                        \
            vr_[ch * 4 + 1] = *(const s16x8*)(VxI_ + off1);                        \
            vr_[ch * 4 + 2] = *(const s16x8*)(VyI_ + off0);                        \
            vr_[ch * 4 + 3] = *(const s16x8*)(VyI_ + off1);                        \
        }                                                                          \
    } while (0)

    // softmax in place + pa redistribution via permlane32_swap (R14-verified)
#define SOFTMAX_PA(sc_, pa_)                                                       \
    do {                                                                           \
        float s_ = 0.f;                                                            \
        _Pragma("unroll")                                                          \
        for (int j = 0; j < 16; ++j) { sc_[j] = exp2f(sc_[j] * SCL); s_ += sc_[j]; } \
        lsum += s_;                                                                \
        _Pragma("unroll")                                                          \
        for (int ch = 0; ch < 2; ++ch) {                                           \
            const int b8 = ch * 8;                                                 \
            unsigned x0 = cvtpk(sc_[b8 + 0], sc_[b8 + 1]);                         \
            unsigned x1 = cvtpk(sc_[b8 + 2], sc_[b8 + 3]);                         \
            unsigned y0 = cvtpk(sc_[b8 + 4], sc_[b8 + 5]);                         \
            unsigned y1 = cvtpk(sc_[b8 + 6], sc_[b8 + 7]);                         \
            asm("v_permlane32_swap_b32 %0, %1" : "+v"(x0), "+v"(y0));              \
            asm("v_permlane32_swap_b32 %0, %1" : "+v"(x1), "+v"(y1));              \
            i32x4 pw;                                                              \
            pw[0] = (int)x0; pw[1] = (int)x1; pw[2] = (int)y0; pw[3] = (int)y1;    \
            pa_[ch] = __builtin_bit_cast(s16x8, pw);                               \
        }                                                                          \
    } while (0)

    // PV accumulate: o += pa_ x vr_  (register-only, 8 MFMA)
#define PV_BLOCK(pa_, vr_)                                                         \
    do {                                                                           \
        _Pragma("unroll")                                                          \
        for (int ch = 0; ch < 2; ++ch) {                                           \
            o1_0 = __builtin_amdgcn_mfma_f32_32x32x16_bf16(pa_[ch], vr_[ch*4+0], o1_0, 0, 0, 0); \
            o1_1 = __builtin_amdgcn_mfma_f32_32x32x16_bf16(pa_[ch], vr_[ch*4+1], o1_1, 0, 0, 0); \
            o2_0 = __builtin_amdgcn_mfma_f32_32x32x16_bf16(pa_[ch], vr_[ch*4+2], o2_0, 0, 0, 0); \
            o2_1 = __builtin_amdgcn_mfma_f32_32x32x16_bf16(pa_[ch], vr_[ch*4+3], o2_1, 0, 0, 0); \
        }                                                                          \
    } while (0)

#define ZERO16(v_) { _Pragma("unroll") for (int j = 0; j < 16; ++j) (v_)[j] = 0.f; }

    STAGE(0, 0);
    __syncthreads();
    int cur = 0;

    for (int kt = 0; kt < NT2; ++kt) {
        if (kt + 1 < NT2) STAGE(kt + 1, cur ^ 1);

        const char* buf = lds + cur * 65536;
        f32x16 scA, scB;
        ZERO16(scA); ZERO16(scB);
        s16x8 pa[2], vrA[8], vrB[8];

        __builtin_amdgcn_s_setprio(1);
        QK_BLOCK(buf, 0, scA);
        QK_BLOCK(buf, 1, scB);           // independent of scA's softmax below
        V_READS(buf, 0, vrA);
        SOFTMAX_PA(scA, pa);             // overlaps QK(h1) tail + V reads
        PV_BLOCK(pa, vrA);
        V_READS(buf, 1, vrB);
        SOFTMAX_PA(scB, pa);             // overlaps PV(h0)
        PV_BLOCK(pa, vrB);               // consumes vrB before barrier (race-safe)
        __builtin_amdgcn_s_setprio(0);

        __syncthreads();    // next buffer staged (vmcnt drained); cur reads done
        cur ^= 1;
    }

#undef STAGE
#undef QK_BLOCK
#undef V_READS
#undef SOFTMAX_PA
#undef PV_BLOCK
#undef ZERO16

    // ---- epilogue: combine ks partials (2 halves of 128 keys), per-q-row inv
    const float lh = lsum + __shfl_xor(lsum, 32);   // 64-key-half sum for q=l31

    __syncthreads();                                 // loop LDS now dead
    float* ex   = (float*)lds;                       // 4*64*33*4B = 33792B
    float* linv = (float*)(lds + 65536);             // 128 per-q-row inverses
    const int exo = (qsub * 64 + lane) * 33;         // stride 33: odd
    float* O1 = Out;
    float* O2 = Out + (size_t)BB * HH * SS * DD;

    // phase 1: tensor X (+ lh)
    if (ks == 1) {
#pragma unroll
        for (int j = 0; j < 16; ++j) { ex[exo + j] = o1_0[j]; ex[exo + 16 + j] = o1_1[j]; }
        ex[exo + 32] = lh;
    }
    __syncthreads();
    if (ks == 0 && hi == 0)
        linv[qsub * 32 + l31] = 1.0f / (lh + ex[exo + 32]);
    __syncthreads();
    if (ks == 0) {
#pragma unroll
        for (int j = 0; j < 16; ++j) {
            const int qr = (j & 3) + 8 * (j >> 2) + 4 * hi;   // output q-row of reg j
            const float invj = linv[qsub * 32 + qr];
            const size_t ob = base + (size_t)(q0 + qsub * 32 + qr) * DD + l31;
            O1[ob]      = (o1_0[j] + ex[exo + j])      * invj;
            O1[ob + 32] = (o1_1[j] + ex[exo + 16 + j]) * invj;
        }
    }
    __syncthreads();
    // phase 2: tensor Y
    if (ks == 1) {
#pragma unroll
        for (int j = 0; j < 16; ++j) { ex[exo + j] = o2_0[j]; ex[exo + 16 + j] = o2_1[j]; }
    }
    __syncthreads();
    if (ks == 0) {
#pragma unroll
        for (int j = 0; j < 16; ++j) {
            const int qr = (j & 3) + 8 * (j >> 2) + 4 * hi;
            const float invj = linv[qsub * 32 + qr];
            const size_t ob = base + (size_t)(q0 + qsub * 32 + qr) * DD + l31;
            O2[ob]      = (o2_0[j] + ex[exo + j])      * invj;
            O2[ob + 32] = (o2_1[j] + ex[exo + 16 + j]) * invj;
        }
    }
}

// ===================== fallback (ws too small; validated R1 path) ============
__global__ __launch_bounds__(256, 2)
void attn_dual_fallback(const float* __restrict__ Qx, const float* __restrict__ Kx,
                        const float* __restrict__ Vx, const float* __restrict__ Qy,
                        const float* __restrict__ Ky, const float* __restrict__ Vy,
                        float* __restrict__ Out)
{
    __shared__ __attribute__((aligned(16))) char lds[40960];
    char* KxL  = lds;
    char* KyL  = lds + 8192;
    char* VtxL = lds + 16384;
    char* VtyL = lds + 24576;

    const int t    = threadIdx.x;
    const int lane = t & 63;
    const int w    = t >> 6;
    const int g    = lane >> 4;
    const int c    = lane & 15;
    char* PL = lds + 32768 + w * 2048;

    const int bid = blockIdx.x;
    const int bh  = bid >> 5;
    const int q0  = (bid & 31) * 64;
    const size_t base = (size_t)bh * SS * DD;

    const int qrowA = q0 + w * 16 + c;
    s16x8 qxf[2], qyf[2];
#pragma unroll
    for (int kk = 0; kk < 2; ++kk) {
        const int d0 = kk * 32 + g * 8;
        const float* qp = Qx + base + (size_t)qrowA * DD + d0;
        const float* qq = Qy + base + (size_t)qrowA * DD + d0;
#pragma unroll
        for (int i = 0; i < 8; ++i) { qxf[kk][i] = f2bf(qp[i]); qyf[kk][i] = f2bf(qq[i]); }
    }

    f32x4 o1[4], o2[4];
#pragma unroll
    for (int n = 0; n < 4; ++n) {
        o1[n] = (f32x4){0.f, 0.f, 0.f, 0.f};
        o2[n] = (f32x4){0.f, 0.f, 0.f, 0.f};
    }
    float m[4]    = {-1e30f, -1e30f, -1e30f, -1e30f};
    float lsum[4] = {0.f, 0.f, 0.f, 0.f};
    const float SCL = 0.09016844005556021f;

    for (int kt = 0; kt < SS / 64; ++kt) {
        __syncthreads();
#pragma unroll
        for (int j = 0; j < 4; ++j) {
            const int f   = t + 256 * j;
            const int row = f >> 4;
            const int c4  = f & 15;
            const size_t gi = base + (size_t)(kt * 64 + row) * DD + c4 * 4;
            const float4 kx = *(const float4*)(Kx + gi);
            const float4 ky = *(const float4*)(Ky + gi);
            const float4 vx = *(const float4*)(Vx + gi);
            const float4 vy = *(const float4*)(Vy + gi);
            s16x4 a; a[0]=f2bf(kx.x); a[1]=f2bf(kx.y); a[2]=f2bf(kx.z); a[3]=f2bf(kx.w);
            *(s16x4*)(KxL + swz(row, c4 * 8)) = a;
            s16x4 b; b[0]=f2bf(ky.x); b[1]=f2bf(ky.y); b[2]=f2bf(ky.z); b[3]=f2bf(ky.w);
            *(s16x4*)(KyL + swz(row, c4 * 8)) = b;
            const int d0 = c4 * 4;
            *(short*)(VtxL + swz(d0 + 0, row * 2)) = f2bf(vx.x);
            *(short*)(VtxL + swz(d0 + 1, row * 2)) = f2bf(vx.y);
            *(short*)(VtxL + swz(d0 + 2, row * 2)) = f2bf(vx.z);
            *(short*)(VtxL + swz(d0 + 3, row * 2)) = f2bf(vx.w);
            *(short*)(VtyL + swz(d0 + 0, row * 2)) = f2bf(vy.x);
            *(short*)(VtyL + swz(d0 + 1, row * 2)) = f2bf(vy.y);
            *(short*)(VtyL + swz(d0 + 2, row * 2)) = f2bf(vy.z);
            *(short*)(VtyL + swz(d0 + 3, row * 2)) = f2bf(vy.w);
        }
        __syncthreads();

        f32x4 sc[4];
#pragma unroll
        for (int n = 0; n < 4; ++n) {
            f32x4 acc = (f32x4){0.f, 0.f, 0.f, 0.f};
            const int keyrow = n * 16 + c;
#pragma unroll
            for (int kk = 0; kk < 2; ++kk) {
                const int off = swz(keyrow, (kk * 32 + g * 8) * 2);
                const s16x8 kxf = *(const s16x8*)(KxL + off);
                const s16x8 kyf = *(const s16x8*)(KyL + off);
                acc = __builtin_amdgcn_mfma_f32_16x16x32_bf16(qxf[kk], kxf, acc, 0, 0, 0);
                acc = __builtin_amdgcn_mfma_f32_16x16x32_bf16(qyf[kk], kyf, acc, 0, 0, 0);
            }
            sc[n] = acc;
        }

#pragma unroll
        for (int r = 0; r < 4; ++r) {
            float v0 = fmaxf(fmaxf(sc[0][r], sc[1][r]), fmaxf(sc[2][r], sc[3][r])) * SCL;
#pragma unroll
            for (int off = 1; off < 16; off <<= 1) v0 = fmaxf(v0, __shfl_xor(v0, off));
            const float mnew = fmaxf(m[r], v0);
            const float cr = exp2f(m[r] - mnew);
            m[r] = mnew;
            float srow = 0.f;
#pragma unroll
            for (int n = 0; n < 4; ++n) {
                const float pp = exp2f(sc[n][r] * SCL - mnew);
                srow += pp;
                *(short*)(PL + swz(g * 4 + r, (n * 16 + c) * 2)) = f2bf(pp);
            }
#pragma unroll
            for (int off = 1; off < 16; off <<= 1) srow += __shfl_xor(srow, off);
            lsum[r] = lsum[r] * cr + srow;
#pragma unroll
            for (int n = 0; n < 4; ++n) { o1[n][r] *= cr; o2[n][r] *= cr; }
        }

        s16x8 pf[2];
#pragma unroll
        for (int kk = 0; kk < 2; ++kk)
            pf[kk] = *(const s16x8*)(PL + swz(c, (kk * 32 + g * 8) * 2));
#pragma unroll
        for (int nd = 0; nd < 4; ++nd) {
            const int drow = nd * 16 + c;
#pragma unroll
            for (int kk = 0; kk < 2; ++kk) {
                const int off = swz(drow, (kk * 32 + g * 8) * 2);
                const s16x8 vxf = *(const s16x8*)(VtxL + off);
                const s16x8 vyf = *(const s16x8*)(VtyL + off);
                o1[nd] = __builtin_amdgcn_mfma_f32_16x16x32_bf16(pf[kk], vxf, o1[nd], 0, 0, 0);
                o2[nd] = __builtin_amdgcn_mfma_f32_16x16x32_bf16(pf[kk], vyf, o2[nd], 0, 0, 0);
            }
        }
    }

    float* O1 = Out;
    float* O2 = Out + (size_t)BB * HH * SS * DD;
#pragma unroll
    for (int r = 0; r < 4; ++r) {
        const float inv = 1.0f / lsum[r];
        const int qrow = q0 + w * 16 + g * 4 + r;
        const size_t ob = base + (size_t)qrow * DD + c;
#pragma unroll
        for (int nd = 0; nd < 4; ++nd) {
            O1[ob + nd * 16] = o1[nd][r] * inv;
            O2[ob + nd * 16] = o2[nd][r] * inv;
        }
    }
}

extern "C" void kernel_launch(void* const* d_in, const int* in_sizes, int n_in,
                              void* d_out, int out_size, void* d_ws, size_t ws_size,
                              hipStream_t stream) {
    const float* Qx = (const float*)d_in[0];
    const float* Kx = (const float*)d_in[1];
    const float* Vx = (const float*)d_in[2];
    const float* Qy = (const float*)d_in[3];
    const float* Ky = (const float*)d_in[4];
    const float* Vy = (const float*)d_in[5];
    float* Out = (float*)d_out;

    if (ws_size >= WS_NEED) {
        char* ws = (char*)d_ws;
        hipLaunchKernelGGL(prep_kv, dim3(2048), dim3(256), 0, stream,
                           Kx, Ky, Vx, Vy, ws);
        hipFuncSetAttribute((const void*)attn_main,
                            hipFuncAttributeMaxDynamicSharedMemorySize, 131072);
        hipLaunchKernelGGL(attn_main, dim3(NBH * (SS / QBLK)), dim3(512), 131072,
                           stream, Qx, Qy, (const char*)ws, Out);
    } else {
        hipLaunchKernelGGL(attn_dual_fallback, dim3(NBH * 32), dim3(256),
                           0, stream, Qx, Kx, Vx, Qy, Ky, Vy, Out);
    }
}

// Round 19
// 58.604 us; speedup vs baseline: 1.2548x; 1.0126x over previous
//
#include <hip/hip_runtime.h>
#include <hip/hip_bf16.h>

typedef __attribute__((ext_vector_type(4)))  float f32x4;
typedef __attribute__((ext_vector_type(16))) float f32x16;
typedef __attribute__((ext_vector_type(8)))  short s16x8;
typedef __attribute__((ext_vector_type(4)))  short s16x4;
typedef __attribute__((ext_vector_type(4)))  int   i32x4;

#define BB 2
#define HH 8
#define SS 2048
#define DD 64
#define QBLK 128
#define NT   32               // 64-key prep images per bh
#define NT2  16               // 128-key tiles in main loop
#define NBH  (BB * HH)        // 16

// ws layout: per-(bh,64-key-tile) 8KB pre-swizzled bf16 LDS images
// (K row-major, V transposed) — R2/R7-verified format, unchanged.
#define WS_KX 0
#define WS_KY ((size_t)NBH * NT * 8192)          // 4 MiB each
#define WS_VX ((size_t)2 * NBH * NT * 8192)
#define WS_VY ((size_t)3 * NBH * NT * 8192)
#define WS_NEED ((size_t)4 * NBH * NT * 8192)    // 16 MiB

// fp32 -> bf16 round-to-nearest-even
__device__ __forceinline__ short f2bf(float x) {
    unsigned u = __builtin_bit_cast(unsigned, x);
    u = (u + 0x7FFFu + ((u >> 16) & 1u)) >> 16;
    return (short)u;
}

// pack two f32 -> one dword of 2 bf16 (RNE)
__device__ __forceinline__ unsigned cvtpk(float lo, float hi) {
    unsigned d;
    asm("v_cvt_pk_bf16_f32 %0, %1, %2" : "=v"(d) : "v"(lo), "v"(hi));
    return d;
}

// XOR swizzle within a 128-byte row (guide G4)
__device__ __forceinline__ int swz(int row, int byteInRow) {
    return row * 128 + (byteInRow ^ ((row & 7) << 4));
}

// 16-byte async global->LDS copy
__device__ __forceinline__ void glds16(const void* g, void* l) {
    __builtin_amdgcn_global_load_lds(
        (const __attribute__((address_space(1))) unsigned*)g,
        (__attribute__((address_space(3))) unsigned*)l, 16, 0, 0);
}

// ------------- fused prepass (R7-verified): K row-major / V transposed -------
__global__ __launch_bounds__(256)
void prep_kv(const float* __restrict__ Kx, const float* __restrict__ Ky,
             const float* __restrict__ Vx, const float* __restrict__ Vy,
             char* __restrict__ ws)
{
    const int b = blockIdx.x;
    if (b < 1024) {
        const int tid  = b * 256 + threadIdx.x;
        const int dblk = tid & 7;
        const int s    = (tid >> 3) & 2047;
        const int bh   = tid >> 14;
        const size_t gi = ((size_t)bh * SS + s) * DD + dblk * 8;
        const int kt = s >> 6, row = s & 63;
        const size_t dst = (size_t)(bh * NT + kt) * 8192 + swz(row, dblk * 16);
        const float* px = Kx + gi;
        const float* py = Ky + gi;
        s16x8 a, bb;
#pragma unroll
        for (int i = 0; i < 8; ++i) { a[i] = f2bf(px[i]); bb[i] = f2bf(py[i]); }
        *(s16x8*)(ws + WS_KX + dst) = a;
        *(s16x8*)(ws + WS_KY + dst) = bb;
    } else {
        const int tid  = (b - 1024) * 256 + threadIdx.x;
        const int d    = tid & 63;
        const int sblk = (tid >> 6) & 7;
        const int kt   = (tid >> 9) & 31;
        const int bh   = tid >> 14;
        const size_t gbase = ((size_t)bh * SS + kt * 64 + sblk * 8) * DD + d;
        s16x8 a, bb;
#pragma unroll
        for (int i = 0; i < 8; ++i) {
            a[i]  = f2bf(Vx[gbase + (size_t)i * DD]);
            bb[i] = f2bf(Vy[gbase + (size_t)i * DD]);
        }
        const size_t dst = (size_t)(bh * NT + kt) * 8192 + swz(d, sblk * 16);
        *(s16x8*)(ws + WS_VX + dst) = a;
        *(s16x8*)(ws + WS_VY + dst) = bb;
    }
}

// ------------------------------- main kernel ---------------------------------
// R16 (verified best) + three register-local latency trims:
//  (1) SCL folded into Q frags -> softmax is exp2(sc) directly (one VALU op
//      off the MFMA->exp2 critical edge; 32 fewer v_mul per thread-tile).
//  (2) The two QK accumulator chains (h0/h1) source-interleaved per dc.
//  (3) Single setprio span per tile.
// Geometry unchanged: KBLK=128, 8 waves = qsub(4) x ks(2), grid 256, 128KB
// dbuf, 16 barriers; all ds_reads consumed before the barrier (R12);
// permlane P-redistribution (R14); R16 epilogue.
__global__ __launch_bounds__(512, 2)
void attn_main(const float* __restrict__ Qx, const float* __restrict__ Qy,
               const char* __restrict__ ws, float* __restrict__ Out)
{
    extern __shared__ char lds[];

    const int t    = threadIdx.x;
    const int lane = t & 63;
    const int w    = t >> 6;      // 0..7
    const int qsub = w & 3;       // 32 q-rows each
    const int ks   = w >> 2;      // 64-key half of the 128-key tile
    const int l31  = lane & 31;
    const int hi   = lane >> 5;   // 0/1

    // XCD-chunked swizzle (256 % 8 == 0, bijective): 32 consecutive per XCD
    int bid = blockIdx.x;
    bid = (bid & 7) * 32 + (bid >> 3);
    const int bh = bid >> 4;
    const int q0 = (bid & 15) * QBLK;
    const size_t base = (size_t)bh * SS * DD;

    const float SCL = 0.09016844005556021f;   // log2(e) / (2*sqrt(64))

    // ---- Q B-frags with SCL pre-folded: col q = lane&31, k = dc*16+hi*8+i
    const int qrow = q0 + qsub * 32 + l31;
    s16x8 qbx[4], qby[4];
#pragma unroll
    for (int dc = 0; dc < 4; ++dc) {
        const int d0 = dc * 16 + hi * 8;
        const float* qp = Qx + base + (size_t)qrow * DD + d0;
        const float* qq = Qy + base + (size_t)qrow * DD + d0;
        const float4 f0 = *(const float4*)qp;
        const float4 f1 = *(const float4*)(qp + 4);
        const float4 h0 = *(const float4*)qq;
        const float4 h1 = *(const float4*)(qq + 4);
        qbx[dc][0]=f2bf(f0.x*SCL); qbx[dc][1]=f2bf(f0.y*SCL); qbx[dc][2]=f2bf(f0.z*SCL); qbx[dc][3]=f2bf(f0.w*SCL);
        qbx[dc][4]=f2bf(f1.x*SCL); qbx[dc][5]=f2bf(f1.y*SCL); qbx[dc][6]=f2bf(f1.z*SCL); qbx[dc][7]=f2bf(f1.w*SCL);
        qby[dc][0]=f2bf(h0.x*SCL); qby[dc][1]=f2bf(h0.y*SCL); qby[dc][2]=f2bf(h0.z*SCL); qby[dc][3]=f2bf(h0.w*SCL);
        qby[dc][4]=f2bf(h1.x*SCL); qby[dc][5]=f2bf(h1.y*SCL); qby[dc][6]=f2bf(h1.z*SCL); qby[dc][7]=f2bf(h1.w*SCL);
    }

    f32x16 o1_0, o1_1, o2_0, o2_1;
#pragma unroll
    for (int j = 0; j < 16; ++j) { o1_0[j] = 0.f; o1_1[j] = 0.f; o2_0[j] = 0.f; o2_1[j] = 0.f; }
    float lsum = 0.f;

    // stage 128-key tile kt_ (2 prep images per tensor) into buffer b_ (64KB)
#define STAGE(kt_, b_)                                                             \
    do {                                                                           \
        const size_t img_ = (size_t)(bh * NT + (kt_) * 2) * 8192 + (size_t)t * 16; \
        char* dst_ = lds + (b_) * 65536 + t * 16;                                  \
        glds16(ws + WS_KX + img_,        dst_);                                    \
        glds16(ws + WS_KX + img_ + 8192, dst_ + 8192);                             \
        glds16(ws + WS_KY + img_,        dst_ + 16384);                            \
        glds16(ws + WS_KY + img_ + 8192, dst_ + 24576);                            \
        glds16(ws + WS_VX + img_,        dst_ + 32768);                            \
        glds16(ws + WS_VX + img_ + 8192, dst_ + 40960);                            \
        glds16(ws + WS_VY + img_,        dst_ + 49152);                            \
        glds16(ws + WS_VY + img_ + 8192, dst_ + 57344);                            \
    } while (0)

    // Both halves' QK chains interleaved per dc (two independent accumulators)
#define QK_BOTH(buf_, scA_, scB_)                                                  \
    do {                                                                           \
        const char* KxI_ = (buf_) + ks * 8192;                                     \
        const char* KyI_ = (buf_) + 16384 + ks * 8192;                             \
        _Pragma("unroll")                                                          \
        for (int dc = 0; dc < 4; ++dc) {                                           \
            const int offA = swz(l31,      dc * 32 + hi * 16);                     \
            const int offB = swz(32 + l31, dc * 32 + hi * 16);                     \
            const s16x8 ka0 = *(const s16x8*)(KxI_ + offA);                        \
            const s16x8 ka1 = *(const s16x8*)(KxI_ + offB);                        \
            const s16x8 kb0 = *(const s16x8*)(KyI_ + offA);                        \
            const s16x8 kb1 = *(const s16x8*)(KyI_ + offB);                        \
            scA_ = __builtin_amdgcn_mfma_f32_32x32x16_bf16(ka0, qbx[dc], scA_, 0, 0, 0); \
            scB_ = __builtin_amdgcn_mfma_f32_32x32x16_bf16(ka1, qbx[dc], scB_, 0, 0, 0); \
            scA_ = __builtin_amdgcn_mfma_f32_32x32x16_bf16(kb0, qby[dc], scA_, 0, 0, 0); \
            scB_ = __builtin_amdgcn_mfma_f32_32x32x16_bf16(kb1, qby[dc], scB_, 0, 0, 0); \
        }                                                                          \
    } while (0)

    // V frag reads for half h_ (8 x ds_read_b128) into vr_[0..7]
#define V_READS(buf_, h_, vr_)                                                     \
    do {                                                                           \
        const char* VxI_ = (buf_) + 32768 + ks * 8192;                             \
        const char* VyI_ = (buf_) + 49152 + ks * 8192;                             \
        _Pragma("unroll")                                                          \
        for (int ch = 0; ch < 2; ++ch) {                                           \
            const int off0 = swz(l31,      (h_) * 64 + ch * 32 + hi * 16);         \
            const int off1 = swz(32 + l31, (h_) * 64 + ch * 32 + hi * 16);         \
            vr_[ch * 4 + 0] = *(const s16x8*)(VxI_ + off0);                        \
            vr_[ch * 4 + 1] = *(const s16x8*)(VxI_ + off1);                        \
            vr_[ch * 4 + 2] = *(const s16x8*)(VyI_ + off0);                        \
            vr_[ch * 4 + 3] = *(const s16x8*)(VyI_ + off1);                        \
        }                                                                          \
    } while (0)

    // softmax (SCL already folded into Q): exp2 directly; permlane repack
#define SOFTMAX_PA(sc_, pa_)                                                       \
    do {                                                                           \
        float s_ = 0.f;                                                            \
        _Pragma("unroll")                                                          \
        for (int j = 0; j < 16; ++j) { sc_[j] = exp2f(sc_[j]); s_ += sc_[j]; }     \
        lsum += s_;                                                                \
        _Pragma("unroll")                                                          \
        for (int ch = 0; ch < 2; ++ch) {                                           \
            const int b8 = ch * 8;                                                 \
            unsigned x0 = cvtpk(sc_[b8 + 0], sc_[b8 + 1]);                         \
            unsigned x1 = cvtpk(sc_[b8 + 2], sc_[b8 + 3]);                         \
            unsigned y0 = cvtpk(sc_[b8 + 4], sc_[b8 + 5]);                         \
            unsigned y1 = cvtpk(sc_[b8 + 6], sc_[b8 + 7]);                         \
            asm("v_permlane32_swap_b32 %0, %1" : "+v"(x0), "+v"(y0));              \
            asm("v_permlane32_swap_b32 %0, %1" : "+v"(x1), "+v"(y1));              \
            i32x4 pw;                                                              \
            pw[0] = (int)x0; pw[1] = (int)x1; pw[2] = (int)y0; pw[3] = (int)y1;    \
            pa_[ch] = __builtin_bit_cast(s16x8, pw);                               \
        }                                                                          \
    } while (0)

    // PV accumulate: o += pa_ x vr_  (register-only, 8 MFMA)
#define PV_BLOCK(pa_, vr_)                                                         \
    do {                                                                           \
        _Pragma("unroll")                                                          \
        for (int ch = 0; ch < 2; ++ch) {                                           \
            o1_0 = __builtin_amdgcn_mfma_f32_32x32x16_bf16(pa_[ch], vr_[ch*4+0], o1_0, 0, 0, 0); \
            o1_1 = __builtin_amdgcn_mfma_f32_32x32x16_bf16(pa_[ch], vr_[ch*4+1], o1_1, 0, 0, 0); \
            o2_0 = __builtin_amdgcn_mfma_f32_32x32x16_bf16(pa_[ch], vr_[ch*4+2], o2_0, 0, 0, 0); \
            o2_1 = __builtin_amdgcn_mfma_f32_32x32x16_bf16(pa_[ch], vr_[ch*4+3], o2_1, 0, 0, 0); \
        }                                                                          \
    } while (0)

#define ZERO16(v_) { _Pragma("unroll") for (int j = 0; j < 16; ++j) (v_)[j] = 0.f; }

    STAGE(0, 0);
    __syncthreads();
    int cur = 0;

    for (int kt = 0; kt < NT2; ++kt) {
        if (kt + 1 < NT2) STAGE(kt + 1, cur ^ 1);

        const char* buf = lds + cur * 65536;
        f32x16 scA, scB;
        ZERO16(scA); ZERO16(scB);
        s16x8 pa[2], vrA[8], vrB[8];

        __builtin_amdgcn_s_setprio(1);
        QK_BOTH(buf, scA, scB);          // two interleaved accumulator chains
        V_READS(buf, 0, vrA);
        SOFTMAX_PA(scA, pa);             // overlaps QK tail + V reads
        PV_BLOCK(pa, vrA);
        V_READS(buf, 1, vrB);
        SOFTMAX_PA(scB, pa);             // overlaps PV(h0)
        PV_BLOCK(pa, vrB);               // consumes vrB before barrier (race-safe)
        __builtin_amdgcn_s_setprio(0);

        __syncthreads();    // next buffer staged (vmcnt drained); cur reads done
        cur ^= 1;
    }

#undef STAGE
#undef QK_BOTH
#undef V_READS
#undef SOFTMAX_PA
#undef PV_BLOCK
#undef ZERO16

    // ---- epilogue (R16-verified): combine ks partials, per-q-row inverse
    const float lh = lsum + __shfl_xor(lsum, 32);   // 64-key-half sum for q=l31

    __syncthreads();                                 // loop LDS now dead
    float* ex   = (float*)lds;                       // 4*64*33*4B = 33792B
    float* linv = (float*)(lds + 65536);             // 128 per-q-row inverses
    const int exo = (qsub * 64 + lane) * 33;         // stride 33: odd
    float* O1 = Out;
    float* O2 = Out + (size_t)BB * HH * SS * DD;

    // phase 1: tensor X (+ lh)
    if (ks == 1) {
#pragma unroll
        for (int j = 0; j < 16; ++j) { ex[exo + j] = o1_0[j]; ex[exo + 16 + j] = o1_1[j]; }
        ex[exo + 32] = lh;
    }
    __syncthreads();
    if (ks == 0 && hi == 0)
        linv[qsub * 32 + l31] = 1.0f / (lh + ex[exo + 32]);
    __syncthreads();
    if (ks == 0) {
#pragma unroll
        for (int j = 0; j < 16; ++j) {
            const int qr = (j & 3) + 8 * (j >> 2) + 4 * hi;   // output q-row of reg j
            const float invj = linv[qsub * 32 + qr];
            const size_t ob = base + (size_t)(q0 + qsub * 32 + qr) * DD + l31;
            O1[ob]      = (o1_0[j] + ex[exo + j])      * invj;
            O1[ob + 32] = (o1_1[j] + ex[exo + 16 + j]) * invj;
        }
    }
    __syncthreads();
    // phase 2: tensor Y
    if (ks == 1) {
#pragma unroll
        for (int j = 0; j < 16; ++j) { ex[exo + j] = o2_0[j]; ex[exo + 16 + j] = o2_1[j]; }
    }
    __syncthreads();
    if (ks == 0) {
#pragma unroll
        for (int j = 0; j < 16; ++j) {
            const int qr = (j & 3) + 8 * (j >> 2) + 4 * hi;
            const float invj = linv[qsub * 32 + qr];
            const size_t ob = base + (size_t)(q0 + qsub * 32 + qr) * DD + l31;
            O2[ob]      = (o2_0[j] + ex[exo + j])      * invj;
            O2[ob + 32] = (o2_1[j] + ex[exo + 16 + j]) * invj;
        }
    }
}

// ===================== fallback (ws too small; validated R1 path) ============
__global__ __launch_bounds__(256, 2)
void attn_dual_fallback(const float* __restrict__ Qx, const float* __restrict__ Kx,
                        const float* __restrict__ Vx, const float* __restrict__ Qy,
                        const float* __restrict__ Ky, const float* __restrict__ Vy,
                        float* __restrict__ Out)
{
    __shared__ __attribute__((aligned(16))) char lds[40960];
    char* KxL  = lds;
    char* KyL  = lds + 8192;
    char* VtxL = lds + 16384;
    char* VtyL = lds + 24576;

    const int t    = threadIdx.x;
    const int lane = t & 63;
    const int w    = t >> 6;
    const int g    = lane >> 4;
    const int c    = lane & 15;
    char* PL = lds + 32768 + w * 2048;

    const int bid = blockIdx.x;
    const int bh  = bid >> 5;
    const int q0  = (bid & 31) * 64;
    const size_t base = (size_t)bh * SS * DD;

    const int qrowA = q0 + w * 16 + c;
    s16x8 qxf[2], qyf[2];
#pragma unroll
    for (int kk = 0; kk < 2; ++kk) {
        const int d0 = kk * 32 + g * 8;
        const float* qp = Qx + base + (size_t)qrowA * DD + d0;
        const float* qq = Qy + base + (size_t)qrowA * DD + d0;
#pragma unroll
        for (int i = 0; i < 8; ++i) { qxf[kk][i] = f2bf(qp[i]); qyf[kk][i] = f2bf(qq[i]); }
    }

    f32x4 o1[4], o2[4];
#pragma unroll
    for (int n = 0; n < 4; ++n) {
        o1[n] = (f32x4){0.f, 0.f, 0.f, 0.f};
        o2[n] = (f32x4){0.f, 0.f, 0.f, 0.f};
    }
    float m[4]    = {-1e30f, -1e30f, -1e30f, -1e30f};
    float lsum[4] = {0.f, 0.f, 0.f, 0.f};
    const float SCL = 0.09016844005556021f;

    for (int kt = 0; kt < SS / 64; ++kt) {
        __syncthreads();
#pragma unroll
        for (int j = 0; j < 4; ++j) {
            const int f   = t + 256 * j;
            const int row = f >> 4;
            const int c4  = f & 15;
            const size_t gi = base + (size_t)(kt * 64 + row) * DD + c4 * 4;
            const float4 kx = *(const float4*)(Kx + gi);
            const float4 ky = *(const float4*)(Ky + gi);
            const float4 vx = *(const float4*)(Vx + gi);
            const float4 vy = *(const float4*)(Vy + gi);
            s16x4 a; a[0]=f2bf(kx.x); a[1]=f2bf(kx.y); a[2]=f2bf(kx.z); a[3]=f2bf(kx.w);
            *(s16x4*)(KxL + swz(row, c4 * 8)) = a;
            s16x4 b; b[0]=f2bf(ky.x); b[1]=f2bf(ky.y); b[2]=f2bf(ky.z); b[3]=f2bf(ky.w);
            *(s16x4*)(KyL + swz(row, c4 * 8)) = b;
            const int d0 = c4 * 4;
            *(short*)(VtxL + swz(d0 + 0, row * 2)) = f2bf(vx.x);
            *(short*)(VtxL + swz(d0 + 1, row * 2)) = f2bf(vx.y);
            *(short*)(VtxL + swz(d0 + 2, row * 2)) = f2bf(vx.z);
            *(short*)(VtxL + swz(d0 + 3, row * 2)) = f2bf(vx.w);
            *(short*)(VtyL + swz(d0 + 0, row * 2)) = f2bf(vy.x);
            *(short*)(VtyL + swz(d0 + 1, row * 2)) = f2bf(vy.y);
            *(short*)(VtyL + swz(d0 + 2, row * 2)) = f2bf(vy.z);
            *(short*)(VtyL + swz(d0 + 3, row * 2)) = f2bf(vy.w);
        }
        __syncthreads();

        f32x4 sc[4];
#pragma unroll
        for (int n = 0; n < 4; ++n) {
            f32x4 acc = (f32x4){0.f, 0.f, 0.f, 0.f};
            const int keyrow = n * 16 + c;
#pragma unroll
            for (int kk = 0; kk < 2; ++kk) {
                const int off = swz(keyrow, (kk * 32 + g * 8) * 2);
                const s16x8 kxf = *(const s16x8*)(KxL + off);
                const s16x8 kyf = *(const s16x8*)(KyL + off);
                acc = __builtin_amdgcn_mfma_f32_16x16x32_bf16(qxf[kk], kxf, acc, 0, 0, 0);
                acc = __builtin_amdgcn_mfma_f32_16x16x32_bf16(qyf[kk], kyf, acc, 0, 0, 0);
            }
            sc[n] = acc;
        }

#pragma unroll
        for (int r = 0; r < 4; ++r) {
            float v0 = fmaxf(fmaxf(sc[0][r], sc[1][r]), fmaxf(sc[2][r], sc[3][r])) * SCL;
#pragma unroll
            for (int off = 1; off < 16; off <<= 1) v0 = fmaxf(v0, __shfl_xor(v0, off));
            const float mnew = fmaxf(m[r], v0);
            const float cr = exp2f(m[r] - mnew);
            m[r] = mnew;
            float srow = 0.f;
#pragma unroll
            for (int n = 0; n < 4; ++n) {
                const float pp = exp2f(sc[n][r] * SCL - mnew);
                srow += pp;
                *(short*)(PL + swz(g * 4 + r, (n * 16 + c) * 2)) = f2bf(pp);
            }
#pragma unroll
            for (int off = 1; off < 16; off <<= 1) srow += __shfl_xor(srow, off);
            lsum[r] = lsum[r] * cr + srow;
#pragma unroll
            for (int n = 0; n < 4; ++n) { o1[n][r] *= cr; o2[n][r] *= cr; }
        }

        s16x8 pf[2];
#pragma unroll
        for (int kk = 0; kk < 2; ++kk)
            pf[kk] = *(const s16x8*)(PL + swz(c, (kk * 32 + g * 8) * 2));
#pragma unroll
        for (int nd = 0; nd < 4; ++nd) {
            const int drow = nd * 16 + c;
#pragma unroll
            for (int kk = 0; kk < 2; ++kk) {
                const int off = swz(drow, (kk * 32 + g * 8) * 2);
                const s16x8 vxf = *(const s16x8*)(VtxL + off);
                const s16x8 vyf = *(const s16x8*)(VtyL + off);
                o1[nd] = __builtin_amdgcn_mfma_f32_16x16x32_bf16(pf[kk], vxf, o1[nd], 0, 0, 0);
                o2[nd] = __builtin_amdgcn_mfma_f32_16x16x32_bf16(pf[kk], vyf, o2[nd], 0, 0, 0);
            }
        }
    }

    float* O1 = Out;
    float* O2 = Out + (size_t)BB * HH * SS * DD;
#pragma unroll
    for (int r = 0; r < 4; ++r) {
        const float inv = 1.0f / lsum[r];
        const int qrow = q0 + w * 16 + g * 4 + r;
        const size_t ob = base + (size_t)qrow * DD + c;
#pragma unroll
        for (int nd = 0; nd < 4; ++nd) {
            O1[ob + nd * 16] = o1[nd][r] * inv;
            O2[ob + nd * 16] = o2[nd][r] * inv;
        }
    }
}

extern "C" void kernel_launch(void* const* d_in, const int* in_sizes, int n_in,
                              void* d_out, int out_size, void* d_ws, size_t ws_size,
                              hipStream_t stream) {
    const float* Qx = (const float*)d_in[0];
    const float* Kx = (const float*)d_in[1];
    const float* Vx = (const float*)d_in[2];
    const float* Qy = (const float*)d_in[3];
    const float* Ky = (const float*)d_in[4];
    const float* Vy = (const float*)d_in[5];
    float* Out = (float*)d_out;

    if (ws_size >= WS_NEED) {
        char* ws = (char*)d_ws;
        hipLaunchKernelGGL(prep_kv, dim3(2048), dim3(256), 0, stream,
                           Kx, Ky, Vx, Vy, ws);
        hipFuncSetAttribute((const void*)attn_main,
                            hipFuncAttributeMaxDynamicSharedMemorySize, 131072);
        hipLaunchKernelGGL(attn_main, dim3(NBH * (SS / QBLK)), dim3(512), 131072,
                           stream, Qx, Qy, (const char*)ws, Out);
    } else {
        hipLaunchKernelGGL(attn_dual_fallback, dim3(NBH * 32), dim3(256),
                           0, stream, Qx, Kx, Vx, Qy, Ky, Vy, Out);
    }
}